// Round 1
// baseline (1785.245 us; speedup 1.0000x reference)
//
#include <hip/hip_runtime.h>
#include <stdint.h>

#define B_ROWS 16384
#define NCLOUD 256
#define QDIM   2048
#define NPROMPT 1024
#define HID    64
#define ODIM   64
#define NSEL   32

typedef unsigned short u16;
typedef __attribute__((ext_vector_type(8))) short short8;
typedef __attribute__((ext_vector_type(4))) float f32x4;

__device__ __forceinline__ u16 f2bf(float x) {
  unsigned u = __float_as_uint(x);
  unsigned r = (u + 0x7fffu + ((u >> 16) & 1u)) >> 16;  // RNE
  return (u16)r;
}
__device__ __forceinline__ float bf2f(u16 h) {
  return __uint_as_float(((unsigned)h) << 16);
}

// ---------------------------------------------------------------------------
// L2-normalize rows of [rows x 2048] f32, split each element into bf16 hi/lo,
// store as [rows][2*2048] u16: cols 0..2047 = hi, 2048..4095 = lo.
// ---------------------------------------------------------------------------
__global__ __launch_bounds__(256) void norm_split_kernel(
    const float* __restrict__ in, u16* __restrict__ out) {
  const int row = blockIdx.x;
  const int t = threadIdx.x;
  const float* rp = in + (size_t)row * QDIM;
  float4 v0 = ((const float4*)rp)[t * 2];
  float4 v1 = ((const float4*)rp)[t * 2 + 1];
  float ss = v0.x*v0.x + v0.y*v0.y + v0.z*v0.z + v0.w*v0.w
           + v1.x*v1.x + v1.y*v1.y + v1.z*v1.z + v1.w*v1.w;
  #pragma unroll
  for (int m = 1; m < 64; m <<= 1) ss += __shfl_xor(ss, m, 64);
  __shared__ float red[4];
  if ((t & 63) == 0) red[t >> 6] = ss;
  __syncthreads();
  float tot = red[0] + red[1] + red[2] + red[3];
  float inv = 1.0f / fmaxf(sqrtf(tot), 1e-12f);  // x / max(||x||, eps)
  float xs[8] = {v0.x, v0.y, v0.z, v0.w, v1.x, v1.y, v1.z, v1.w};
  u16 hs[8], ls[8];
  #pragma unroll
  for (int j = 0; j < 8; ++j) {
    float x = xs[j] * inv;
    u16 h = f2bf(x);
    hs[j] = h;
    ls[j] = f2bf(x - bf2f(h));
  }
  u16* ob = out + (size_t)row * (2 * QDIM);
  *(uint4*)(ob + t * 8)        = *(const uint4*)hs;
  *(uint4*)(ob + QDIM + t * 8) = *(const uint4*)ls;
}

// ---------------------------------------------------------------------------
// P1[n][h] = sum_k prompts[n][k] * w1[h][k]   (1024 x 64, K=1024)
// ---------------------------------------------------------------------------
__global__ __launch_bounds__(256) void p1_kernel(
    const float* __restrict__ prompts, const float* __restrict__ w1,
    float* __restrict__ P1) {
  const int n = blockIdx.x;
  const int t = threadIdx.x;
  const int h = t & 63, q = t >> 6;            // 4 K-quarters of 256
  const float* pr = prompts + (size_t)n * 1024 + q * 256;
  const float* wr = w1 + (size_t)h * 1024 + q * 256;
  float acc = 0.f;
  #pragma unroll 4
  for (int i = 0; i < 256; ++i) acc += pr[i] * wr[i];
  __shared__ float red[256];
  red[t] = acc;
  __syncthreads();
  if (t < 64) P1[(size_t)n * 64 + t] = red[t] + red[t + 64] + red[t + 128] + red[t + 192];
}

// ---------------------------------------------------------------------------
// Split-bf16 GEMM: S[m][n] = 0.5 - 0.5 * sum_k qn[m][k]*kn[n][k]
// A = [16384][4096] (hi|lo), B = [1024][4096] (hi|lo), virtual K = 6144:
//   kt  0..31: A.hi x B.hi ; 32..63: A.hi x B.lo ; 64..95: A.lo x B.hi
// m97-structure: 128x128 tile, BK=64, 4 waves (2x2, 64x64 each), 16x16x32 MFMA.
// ---------------------------------------------------------------------------
__global__ __launch_bounds__(256) void gemm_split_kernel(
    const u16* __restrict__ A, const u16* __restrict__ B,
    float* __restrict__ S) {
  __shared__ u16 sA[128][64];
  __shared__ u16 sB[128][64];

  // XCD-aware bijective swizzle (nwg = 1024 = 8*128)
  const int flat = blockIdx.y * 8 + blockIdx.x;
  const int v = (flat & 7) * 128 + (flat >> 3);
  const int bx = v & 7, by = v >> 3;
  const int m0 = by * 128, n0 = bx * 128;

  const int tid = threadIdx.x;
  const int lane = tid & 63, w = tid >> 6;
  const int wrow = w >> 1, wcol = w & 1;

  f32x4 acc[4][4] = {};

  const int srow = w * 32 + (lane >> 3);   // staging row (+ c*8)
  const int scol = (lane & 7) * 8;         // staging col (u16 elems)

  for (int kt = 0; kt < 96; ++kt) {
    const int term = kt >> 5;
    const int ko = (kt & 31) * 64;
    const int acol = ((term == 2) ? 2048 : 0) + ko;
    const int bcol = ((term == 1) ? 2048 : 0) + ko;
    #pragma unroll
    for (int c = 0; c < 4; ++c) {
      const int r = srow + c * 8;
      const u16* gp = A + (size_t)(m0 + r) * 4096 + acol + scol;
      __builtin_amdgcn_global_load_lds(
          (const __attribute__((address_space(1))) void*)gp,
          (__attribute__((address_space(3))) void*)&sA[r][scol], 16, 0, 0);
    }
    #pragma unroll
    for (int c = 0; c < 4; ++c) {
      const int r = srow + c * 8;
      const u16* gp = B + (size_t)(n0 + r) * 4096 + bcol + scol;
      __builtin_amdgcn_global_load_lds(
          (const __attribute__((address_space(1))) void*)gp,
          (__attribute__((address_space(3))) void*)&sB[r][scol], 16, 0, 0);
    }
    __syncthreads();   // compiler emits vmcnt(0) drain before barrier
    #pragma unroll
    for (int ks = 0; ks < 2; ++ks) {
      const int kk = ks * 32 + (lane >> 4) * 8;
      short8 aF[4], bF[4];
      #pragma unroll
      for (int mi = 0; mi < 4; ++mi)
        aF[mi] = *(const short8*)&sA[wrow * 64 + mi * 16 + (lane & 15)][kk];
      #pragma unroll
      for (int ni = 0; ni < 4; ++ni)
        bF[ni] = *(const short8*)&sB[wcol * 64 + ni * 16 + (lane & 15)][kk];
      #pragma unroll
      for (int mi = 0; mi < 4; ++mi)
        #pragma unroll
        for (int ni = 0; ni < 4; ++ni)
          acc[mi][ni] = __builtin_amdgcn_mfma_f32_16x16x32_bf16(
              aF[mi], bF[ni], acc[mi][ni], 0, 0, 0);
    }
    __syncthreads();
  }
  // epilogue: C/D layout col=lane&15, row=(lane>>4)*4+reg (m89-verified)
  const int crow0 = m0 + wrow * 64 + (lane >> 4) * 4;
  const int ccol0 = n0 + wcol * 64 + (lane & 15);
  #pragma unroll
  for (int mi = 0; mi < 4; ++mi)
    #pragma unroll
    for (int ni = 0; ni < 4; ++ni)
      #pragma unroll
      for (int r = 0; r < 4; ++r)
        S[(size_t)(crow0 + mi * 16 + r) * 1024 + ccol0 + ni * 16] =
            0.5f - 0.5f * acc[mi][ni][r];
}

// ---------------------------------------------------------------------------
// Per row b: bitonic-sort 1024 (dist,idx) keys ascending, take 32 smallest,
// softmax(1-d), h = relu((1/32) sum score*P1[idx] + b1), o = h@w2.T + b2,
// write selected_dist[32] and broadcast o over 256 cloud points.
// ---------------------------------------------------------------------------
__global__ __launch_bounds__(256) void topk_mlp_bcast_kernel(
    const float* __restrict__ S, const float* __restrict__ P1,
    const float* __restrict__ b1, const float* __restrict__ w2,
    const float* __restrict__ b2, float* __restrict__ xout,
    float* __restrict__ sdout) {
  const int b = blockIdx.x;
  const int t = threadIdx.x;
  __shared__ unsigned long long keys[1024];
  __shared__ float score_s[NSEL];
  __shared__ int idx_s[NSEL];
  __shared__ float h_s[HID];
  __shared__ float o_s[ODIM];

  const float* Sr = S + (size_t)b * 1024;
  #pragma unroll
  for (int e = t; e < 1024; e += 256) {
    float d = Sr[e];
    unsigned u = __float_as_uint(d);
    u = (u & 0x80000000u) ? ~u : (u | 0x80000000u);  // sortable uint
    keys[e] = ((unsigned long long)u << 32) | (unsigned)e;
  }
  __syncthreads();
  for (int k = 2; k <= 1024; k <<= 1) {
    for (int j = k >> 1; j > 0; j >>= 1) {
      #pragma unroll
      for (int e = t; e < 1024; e += 256) {
        const int l = e ^ j;
        if (l > e) {
          unsigned long long a = keys[e], c = keys[l];
          const bool asc = ((e & k) == 0);
          if ((a > c) == asc) { keys[e] = c; keys[l] = a; }
        }
      }
      __syncthreads();
    }
  }
  if (t < NSEL) {
    unsigned long long kv = keys[t];
    unsigned u = (unsigned)(kv >> 32);
    unsigned bits = (u & 0x80000000u) ? (u ^ 0x80000000u) : ~u;
    float d = __uint_as_float(bits);
    sdout[(size_t)b * NSEL + t] = d;
    float d0 = __shfl(d, 0, 32);
    float e_ = __expf(d0 - d);                 // softmax(1-d), max = 1-d0
    float sum = e_;
    #pragma unroll
    for (int m = 1; m < 32; m <<= 1) sum += __shfl_xor(sum, m, 32);
    score_s[t] = e_ / sum;
    idx_s[t] = (int)(kv & 0xffffffffu);
  }
  __syncthreads();
  if (t < HID) {
    float acc = 0.f;
    #pragma unroll
    for (int j = 0; j < NSEL; ++j)
      acc += score_s[j] * P1[(size_t)idx_s[j] * HID + t];
    h_s[t] = fmaxf(acc * (1.0f / NSEL) + b1[t], 0.0f);
  }
  __syncthreads();
  if (t < ODIM) {
    float acc = b2[t];
    #pragma unroll
    for (int h = 0; h < HID; ++h) acc += h_s[h] * w2[t * HID + h];
    o_s[t] = acc;
  }
  __syncthreads();
  const float4 myv = ((const float4*)o_s)[t & 15];
  float4* xr = (float4*)(xout + (size_t)b * (NCLOUD * ODIM));
  #pragma unroll
  for (int i = t; i < NCLOUD * ODIM / 4; i += 256) xr[i] = myv;
}

// ---------------------------------------------------------------------------
extern "C" void kernel_launch(void* const* d_in, const int* in_sizes, int n_in,
                              void* d_out, int out_size, void* d_ws, size_t ws_size,
                              hipStream_t stream) {
  // inputs: 0 cloud (unused), 1 query, 2 keys, 3 prompts, 4 w1, 5 b1, 6 w2,
  //         7 b2, 8 num_select (==32, hardcoded)
  const float* query   = (const float*)d_in[1];
  const float* keys    = (const float*)d_in[2];
  const float* prompts = (const float*)d_in[3];
  const float* w1      = (const float*)d_in[4];
  const float* b1      = (const float*)d_in[5];
  const float* w2      = (const float*)d_in[6];
  const float* b2      = (const float*)d_in[7];

  char* ws = (char*)d_ws;
  u16*   Abig = (u16*)ws;                                       // 134217728 B
  u16*   Bbig = (u16*)(ws + 134217728);                         //   8388608 B
  float* P1   = (float*)(ws + 134217728 + 8388608);             //    262144 B
  float* S    = (float*)(ws + 134217728 + 8388608 + 262144);    //  67108864 B

  float* xout  = (float*)d_out;
  float* sdout = (float*)d_out + (size_t)B_ROWS * NCLOUD * ODIM;

  norm_split_kernel<<<B_ROWS, 256, 0, stream>>>(query, Abig);
  norm_split_kernel<<<NPROMPT, 256, 0, stream>>>(keys, Bbig);
  p1_kernel<<<NPROMPT, 256, 0, stream>>>(prompts, w1, P1);
  gemm_split_kernel<<<dim3(8, 128), 256, 0, stream>>>(Abig, Bbig, S);
  topk_mlp_bcast_kernel<<<B_ROWS, 256, 0, stream>>>(S, P1, b1, w2, b2, xout, sdout);
}

// Round 2
// 1566.799 us; speedup vs baseline: 1.1394x; 1.1394x over previous
//
#include <hip/hip_runtime.h>
#include <stdint.h>

#define B_ROWS 16384
#define NCLOUD 256
#define QDIM   2048
#define NPROMPT 1024
#define HID    64
#define ODIM   64
#define NSEL   32

typedef unsigned short u16;
typedef unsigned long long u64;
typedef __attribute__((ext_vector_type(8))) short short8;
typedef __attribute__((ext_vector_type(4))) float f32x4;

__device__ __forceinline__ u16 f2bf(float x) {
  unsigned u = __float_as_uint(x);
  unsigned r = (u + 0x7fffu + ((u >> 16) & 1u)) >> 16;  // RNE
  return (u16)r;
}
__device__ __forceinline__ float bf2f(u16 h) {
  return __uint_as_float(((unsigned)h) << 16);
}

// ---------------------------------------------------------------------------
// L2-normalize rows of [rows x 2048] f32, split each element into bf16 hi/lo,
// store as [rows][2*2048] u16: cols 0..2047 = hi, 2048..4095 = lo.
// Fully coalesced: float4 loads at lane-stride 16B, ushort4 stores at 8B.
// ---------------------------------------------------------------------------
__global__ __launch_bounds__(256) void norm_split_kernel(
    const float* __restrict__ in, u16* __restrict__ out) {
  const int row = blockIdx.x;
  const int t = threadIdx.x;
  const float* rp = in + (size_t)row * QDIM;
  float4 v0 = ((const float4*)rp)[t];          // elems 4t .. 4t+3
  float4 v1 = ((const float4*)rp)[t + 256];    // elems 1024+4t ..
  float ss = v0.x*v0.x + v0.y*v0.y + v0.z*v0.z + v0.w*v0.w
           + v1.x*v1.x + v1.y*v1.y + v1.z*v1.z + v1.w*v1.w;
  #pragma unroll
  for (int m = 1; m < 64; m <<= 1) ss += __shfl_xor(ss, m, 64);
  __shared__ float red[4];
  if ((t & 63) == 0) red[t >> 6] = ss;
  __syncthreads();
  float tot = red[0] + red[1] + red[2] + red[3];
  float inv = 1.0f / fmaxf(sqrtf(tot), 1e-12f);  // x / max(||x||, eps)
  float x0[4] = {v0.x, v0.y, v0.z, v0.w};
  float x1[4] = {v1.x, v1.y, v1.z, v1.w};
  u16 h0[4], h1[4], l0[4], l1[4];
  #pragma unroll
  for (int j = 0; j < 4; ++j) {
    float a = x0[j] * inv;
    h0[j] = f2bf(a); l0[j] = f2bf(a - bf2f(h0[j]));
    float b = x1[j] * inv;
    h1[j] = f2bf(b); l1[j] = f2bf(b - bf2f(h1[j]));
  }
  u16* ob = out + (size_t)row * (2 * QDIM);
  *(ushort4*)(ob + t * 4)               = *(const ushort4*)h0;  // hi, elems 4t..
  *(ushort4*)(ob + 1024 + t * 4)        = *(const ushort4*)h1;
  *(ushort4*)(ob + QDIM + t * 4)        = *(const ushort4*)l0;  // lo
  *(ushort4*)(ob + QDIM + 1024 + t * 4) = *(const ushort4*)l1;
}

// ---------------------------------------------------------------------------
// P1[n][h] = sum_k prompts[n][k] * w1[h][k]   (1024 x 64, K=1024)
// One block per prompt n; wave w handles h = hb*4 + w; coalesced float4 loads.
// ---------------------------------------------------------------------------
__global__ __launch_bounds__(256) void p1_kernel(
    const float* __restrict__ prompts, const float* __restrict__ w1,
    float* __restrict__ P1) {
  const int n = blockIdx.x;
  const int wid = threadIdx.x >> 6, lane = threadIdx.x & 63;
  const float4* pr = (const float4*)(prompts + (size_t)n * 1024);
  for (int hb = 0; hb < 16; ++hb) {
    const int h = hb * 4 + wid;
    const float4* wr = (const float4*)(w1 + (size_t)h * 1024);
    float acc = 0.f;
    #pragma unroll
    for (int i = 0; i < 4; ++i) {
      float4 a = pr[i * 64 + lane];
      float4 b = wr[i * 64 + lane];
      acc += a.x * b.x + a.y * b.y + a.z * b.z + a.w * b.w;
    }
    #pragma unroll
    for (int s = 1; s < 64; s <<= 1) acc += __shfl_xor(acc, s, 64);
    if (lane == 0) P1[(size_t)n * 64 + h] = acc;
  }
}

// ---------------------------------------------------------------------------
// Split-bf16 GEMM: S[m][n] = 0.5 - 0.5 * sum_k qn[m][k]*kn[n][k]
// A = [16384][4096] (hi|lo), B = [1024][4096] (hi|lo), virtual K = 6144:
//   kt  0..31: A.hi x B.hi ; 32..63: A.hi x B.lo ; 64..95: A.lo x B.hi
// m97-structure: 128x128 tile, BK=64, 4 waves (2x2, 64x64 each), 16x16x32 MFMA.
// (unchanged from round 1 — verified correct)
// ---------------------------------------------------------------------------
__global__ __launch_bounds__(256) void gemm_split_kernel(
    const u16* __restrict__ A, const u16* __restrict__ B,
    float* __restrict__ S) {
  __shared__ u16 sA[128][64];
  __shared__ u16 sB[128][64];

  // XCD-aware bijective swizzle (nwg = 1024 = 8*128)
  const int flat = blockIdx.y * 8 + blockIdx.x;
  const int v = (flat & 7) * 128 + (flat >> 3);
  const int bx = v & 7, by = v >> 3;
  const int m0 = by * 128, n0 = bx * 128;

  const int tid = threadIdx.x;
  const int lane = tid & 63, w = tid >> 6;
  const int wrow = w >> 1, wcol = w & 1;

  f32x4 acc[4][4] = {};

  const int srow = w * 32 + (lane >> 3);   // staging row (+ c*8)
  const int scol = (lane & 7) * 8;         // staging col (u16 elems)

  for (int kt = 0; kt < 96; ++kt) {
    const int term = kt >> 5;
    const int ko = (kt & 31) * 64;
    const int acol = ((term == 2) ? 2048 : 0) + ko;
    const int bcol = ((term == 1) ? 2048 : 0) + ko;
    #pragma unroll
    for (int c = 0; c < 4; ++c) {
      const int r = srow + c * 8;
      const u16* gp = A + (size_t)(m0 + r) * 4096 + acol + scol;
      __builtin_amdgcn_global_load_lds(
          (const __attribute__((address_space(1))) void*)gp,
          (__attribute__((address_space(3))) void*)&sA[r][scol], 16, 0, 0);
    }
    #pragma unroll
    for (int c = 0; c < 4; ++c) {
      const int r = srow + c * 8;
      const u16* gp = B + (size_t)(n0 + r) * 4096 + bcol + scol;
      __builtin_amdgcn_global_load_lds(
          (const __attribute__((address_space(1))) void*)gp,
          (__attribute__((address_space(3))) void*)&sB[r][scol], 16, 0, 0);
    }
    __syncthreads();
    #pragma unroll
    for (int ks = 0; ks < 2; ++ks) {
      const int kk = ks * 32 + (lane >> 4) * 8;
      short8 aF[4], bF[4];
      #pragma unroll
      for (int mi = 0; mi < 4; ++mi)
        aF[mi] = *(const short8*)&sA[wrow * 64 + mi * 16 + (lane & 15)][kk];
      #pragma unroll
      for (int ni = 0; ni < 4; ++ni)
        bF[ni] = *(const short8*)&sB[wcol * 64 + ni * 16 + (lane & 15)][kk];
      #pragma unroll
      for (int mi = 0; mi < 4; ++mi)
        #pragma unroll
        for (int ni = 0; ni < 4; ++ni)
          acc[mi][ni] = __builtin_amdgcn_mfma_f32_16x16x32_bf16(
              aF[mi], bF[ni], acc[mi][ni], 0, 0, 0);
    }
    __syncthreads();
  }
  // epilogue: C/D layout col=lane&15, row=(lane>>4)*4+reg (m89-verified)
  const int crow0 = m0 + wrow * 64 + (lane >> 4) * 4;
  const int ccol0 = n0 + wcol * 64 + (lane & 15);
  #pragma unroll
  for (int mi = 0; mi < 4; ++mi)
    #pragma unroll
    for (int ni = 0; ni < 4; ++ni)
      #pragma unroll
      for (int r = 0; r < 4; ++r)
        S[(size_t)(crow0 + mi * 16 + r) * 1024 + ccol0 + ni * 16] =
            0.5f - 0.5f * acc[mi][ni][r];
}

// ---------------------------------------------------------------------------
// Sort-free top-32 + softmax + MLP + broadcast. One WAVE per row, no LDS,
// no barriers. 64 lanes x 16 u64 keys in registers; 32 rounds of wave-min
// extraction (keys unique since idx is packed in low bits -> exactly one
// winner lane per round; ties resolve to lower idx, matching lax.top_k).
// ---------------------------------------------------------------------------
__global__ __launch_bounds__(256) void topk_mlp_bcast_kernel(
    const float* __restrict__ S, const float* __restrict__ P1,
    const float* __restrict__ b1, const float* __restrict__ w2,
    const float* __restrict__ b2, float* __restrict__ xout,
    float* __restrict__ sdout) {
  const int wid = threadIdx.x >> 6;
  const int lane = threadIdx.x & 63;
  const int b = blockIdx.x * 4 + wid;

  const float* Sr = S + (size_t)b * NPROMPT;
  u64 k[16];
  #pragma unroll
  for (int i = 0; i < 4; ++i) {
    float4 v = ((const float4*)Sr)[i * 64 + lane];   // coalesced 1 KB/inst
    const int base = (i * 64 + lane) * 4;
    float vv[4] = {v.x, v.y, v.z, v.w};
    #pragma unroll
    for (int j = 0; j < 4; ++j) {
      unsigned u = __float_as_uint(vv[j]);
      u = (u & 0x80000000u) ? ~u : (u | 0x80000000u);  // sortable uint
      k[i * 4 + j] = ((u64)u << 32) | (unsigned)(base + j);
    }
  }
  u64 m = k[0];
  #pragma unroll
  for (int i = 1; i < 16; ++i) m = (k[i] < m) ? k[i] : m;

  u64 sel = 0;
  for (int r = 0; r < NSEL; ++r) {
    u64 g = m;
    #pragma unroll
    for (int s = 1; s < 64; s <<= 1) {
      u64 o = __shfl_xor(g, s, 64);
      g = (o < g) ? o : g;
    }
    if ((lane & 31) == r) sel = g;      // lanes 0..31 collect ascending list
    if (m == g) {                        // exactly one winner lane
      #pragma unroll
      for (int i = 0; i < 16; ++i)
        if (k[i] == g) k[i] = 0xFFFFFFFFFFFFFFFFull;
      m = k[0];
      #pragma unroll
      for (int i = 1; i < 16; ++i) m = (k[i] < m) ? k[i] : m;
    }
  }

  // decode (both 32-lane halves hold identical sel lists)
  unsigned u = (unsigned)(sel >> 32);
  unsigned bits = (u & 0x80000000u) ? (u ^ 0x80000000u) : ~u;
  float d = __uint_as_float(bits);
  int idx = (int)(sel & 0xffffffffu);
  if (lane < NSEL) sdout[(size_t)b * NSEL + lane] = d;

  // softmax(1 - d) over the 32 selected (max at d0, the smallest dist)
  float d0 = __shfl(d, 0, 32);
  float e = __expf(d0 - d);
  float sum = e;
  #pragma unroll
  for (int s = 1; s < 32; s <<= 1) sum += __shfl_xor(sum, s, 32);
  float score = e / sum;

  // h[lane] = relu((1/32) * sum_r score_r * P1[idx_r][lane] + b1[lane])
  float acc = 0.f;
  #pragma unroll
  for (int r = 0; r < NSEL; ++r) {
    float sr = __shfl(score, r, 32);
    int ir = __shfl(idx, r, 32);
    acc = fmaf(sr, P1[(size_t)ir * HID + lane], acc);
  }
  float h = fmaxf(acc * (1.0f / NSEL) + b1[lane], 0.0f);

  // o[lane] = b2[lane] + sum_hh h[hh] * w2[lane][hh]
  float o = b2[lane];
  #pragma unroll
  for (int hh = 0; hh < 64; ++hh)
    o = fmaf(__shfl(h, hh, 64), w2[lane * HID + hh], o);

  // broadcast o over 256 cloud points: per-lane float4 via 4 shuffles
  const int src = (lane & 15) * 4;
  float4 f;
  f.x = __shfl(o, src + 0, 64);
  f.y = __shfl(o, src + 1, 64);
  f.z = __shfl(o, src + 2, 64);
  f.w = __shfl(o, src + 3, 64);
  float4* xr = (float4*)(xout + (size_t)b * (NCLOUD * ODIM));
  #pragma unroll 4
  for (int i = 0; i < 64; ++i) xr[i * 64 + lane] = f;   // coalesced 1 KB/inst
}

// ---------------------------------------------------------------------------
extern "C" void kernel_launch(void* const* d_in, const int* in_sizes, int n_in,
                              void* d_out, int out_size, void* d_ws, size_t ws_size,
                              hipStream_t stream) {
  const float* query   = (const float*)d_in[1];
  const float* keys    = (const float*)d_in[2];
  const float* prompts = (const float*)d_in[3];
  const float* w1      = (const float*)d_in[4];
  const float* b1      = (const float*)d_in[5];
  const float* w2      = (const float*)d_in[6];
  const float* b2      = (const float*)d_in[7];

  char* ws = (char*)d_ws;
  u16*   Abig = (u16*)ws;                                       // 134217728 B
  u16*   Bbig = (u16*)(ws + 134217728);                         //   8388608 B
  float* P1   = (float*)(ws + 134217728 + 8388608);             //    262144 B
  float* S    = (float*)(ws + 134217728 + 8388608 + 262144);    //  67108864 B

  float* xout  = (float*)d_out;
  float* sdout = (float*)d_out + (size_t)B_ROWS * NCLOUD * ODIM;

  norm_split_kernel<<<B_ROWS, 256, 0, stream>>>(query, Abig);
  norm_split_kernel<<<NPROMPT, 256, 0, stream>>>(keys, Bbig);
  p1_kernel<<<NPROMPT, 256, 0, stream>>>(prompts, w1, P1);
  gemm_split_kernel<<<dim3(8, 128), 256, 0, stream>>>(Abig, Bbig, S);
  topk_mlp_bcast_kernel<<<B_ROWS / 4, 256, 0, stream>>>(S, P1, b1, w2, b2, xout, sdout);
}

// Round 4
// 1410.919 us; speedup vs baseline: 1.2653x; 1.1105x over previous
//
#include <hip/hip_runtime.h>
#include <stdint.h>

#define B_ROWS 16384
#define NCLOUD 256
#define QDIM   2048
#define NPROMPT 1024
#define HID    64
#define ODIM   64
#define NSEL   32

typedef unsigned short u16;
typedef unsigned int u32;
typedef unsigned long long u64;
typedef __attribute__((ext_vector_type(8))) short short8;
typedef __attribute__((ext_vector_type(4))) float f32x4;

__device__ __forceinline__ u16 f2bf(float x) {
  unsigned u = __float_as_uint(x);
  unsigned r = (u + 0x7fffu + ((u >> 16) & 1u)) >> 16;  // RNE
  return (u16)r;
}
__device__ __forceinline__ float bf2f(u16 h) {
  return __uint_as_float(((unsigned)h) << 16);
}

// ---------------------------------------------------------------------------
// L2-normalize rows of [rows x 2048] f32, split into bf16 hi/lo:
// out[row][0..2047]=hi, [2048..4095]=lo. (verified R2)
// ---------------------------------------------------------------------------
__global__ __launch_bounds__(256) void norm_split_kernel(
    const float* __restrict__ in, u16* __restrict__ out) {
  const int row = blockIdx.x;
  const int t = threadIdx.x;
  const float* rp = in + (size_t)row * QDIM;
  float4 v0 = ((const float4*)rp)[t];
  float4 v1 = ((const float4*)rp)[t + 256];
  float ss = v0.x*v0.x + v0.y*v0.y + v0.z*v0.z + v0.w*v0.w
           + v1.x*v1.x + v1.y*v1.y + v1.z*v1.z + v1.w*v1.w;
  #pragma unroll
  for (int m = 1; m < 64; m <<= 1) ss += __shfl_xor(ss, m, 64);
  __shared__ float red[4];
  if ((t & 63) == 0) red[t >> 6] = ss;
  __syncthreads();
  float tot = red[0] + red[1] + red[2] + red[3];
  float inv = 1.0f / fmaxf(sqrtf(tot), 1e-12f);
  float x0[4] = {v0.x, v0.y, v0.z, v0.w};
  float x1[4] = {v1.x, v1.y, v1.z, v1.w};
  u16 h0[4], h1[4], l0[4], l1[4];
  #pragma unroll
  for (int j = 0; j < 4; ++j) {
    float a = x0[j] * inv;
    h0[j] = f2bf(a); l0[j] = f2bf(a - bf2f(h0[j]));
    float b = x1[j] * inv;
    h1[j] = f2bf(b); l1[j] = f2bf(b - bf2f(h1[j]));
  }
  u16* ob = out + (size_t)row * (2 * QDIM);
  *(ushort4*)(ob + t * 4)               = *(const ushort4*)h0;
  *(ushort4*)(ob + 1024 + t * 4)        = *(const ushort4*)h1;
  *(ushort4*)(ob + QDIM + t * 4)        = *(const ushort4*)l0;
  *(ushort4*)(ob + QDIM + 1024 + t * 4) = *(const ushort4*)l1;
}

// ---------------------------------------------------------------------------
// P1[n][h] = sum_k prompts[n][k] * w1[h][k]  (verified R2)
// ---------------------------------------------------------------------------
__global__ __launch_bounds__(256) void p1_kernel(
    const float* __restrict__ prompts, const float* __restrict__ w1,
    float* __restrict__ P1) {
  const int n = blockIdx.x;
  const int wid = threadIdx.x >> 6, lane = threadIdx.x & 63;
  const float4* pr = (const float4*)(prompts + (size_t)n * 1024);
  for (int hb = 0; hb < 16; ++hb) {
    const int h = hb * 4 + wid;
    const float4* wr = (const float4*)(w1 + (size_t)h * 1024);
    float acc = 0.f;
    #pragma unroll
    for (int i = 0; i < 4; ++i) {
      float4 a = pr[i * 64 + lane];
      float4 b = wr[i * 64 + lane];
      acc += a.x * b.x + a.y * b.y + a.z * b.z + a.w * b.w;
    }
    #pragma unroll
    for (int s = 1; s < 64; s <<= 1) acc += __shfl_xor(acc, s, 64);
    if (lane == 0) P1[(size_t)n * 64 + h] = acc;
  }
}

// ---------------------------------------------------------------------------
// 256x256 8-phase split-bf16 GEMM (T2 swizzle + T3/T4 counted vmcnt + T5).
// S[m][n] = 0.5 - 0.5 * sum_k qn[m][k]*kn[n][k], virtual K = 96 tiles of 64:
//   kt 0..31: A.hi x B.hi ; 32..63: A.hi x B.lo ; 64..95: A.lo x B.hi
// 512 thr = 8 waves (2m x 4n); per-wave out 128x64.
// LDS slots sH[0..7] (16KB each): 0/1 = A buf0 h0/h1, 2/3 = A buf1 h0/h1,
//                                 4/5 = B buf0 h0/h1, 6/7 = B buf1 h0/h1.
// Schedule: phases q0..q3 of blk0 compute tile t0=2i (buf0), blk1 tile t1
// (buf1). Stages: blk0 q0/q1: A(t1)->sH[2,3]; q2/q3: B(t0+2)->sH[4,5];
//                 blk1 q0/q1: A(t0+2)->sH[0,1]; q2/q3: B(t1+2)->sH[6,7].
// vmcnt(4) before the barrier at q3 of each blk (retires exactly the A/B
// half-tiles the next blk reads; leaves the 2 newest B half-tiles in flight).
// LDS swizzle: byte ^= (row&7)<<4, applied on global source AND ds_read.
// ---------------------------------------------------------------------------
#define FENCE() asm volatile("" ::: "memory")
#define BARRIER() do { FENCE(); __builtin_amdgcn_s_barrier(); FENCE(); } while (0)

__device__ __forceinline__ void stage_half(const u16* __restrict__ gbase,
                                           int grow0, int gcol0,
                                           u16* slot, int tid) {
  #pragma unroll
  for (int sel = 0; sel < 2; ++sel) {
    const int o = sel * 8192 + tid * 16;           // LDS byte offset (linear)
    const int row = o >> 7;                        // 0..127
    const int c = o & 127;
    const int cs = c ^ ((row & 7) << 4);           // inverse-swizzled source
    const u16* src = gbase + (size_t)(grow0 + row) * 4096 + gcol0 + (cs >> 1);
    __builtin_amdgcn_global_load_lds(
        (const __attribute__((address_space(1))) void*)src,
        (__attribute__((address_space(3))) void*)((char*)slot + o), 16, 0, 0);
  }
}

__device__ __forceinline__ int kcolA(int kt) {
  return ((kt >> 5) == 2 ? 2048 : 0) + (kt & 31) * 64;
}
__device__ __forceinline__ int kcolB(int kt) {
  return ((kt >> 5) == 1 ? 2048 : 0) + (kt & 31) * 64;
}

__global__ __launch_bounds__(512, 2) void gemm8p_kernel(
    const u16* __restrict__ A, const u16* __restrict__ B,
    float* __restrict__ S) {
  __shared__ u16 sH[8][8192];

  // XCD-aware bijective swizzle (nwg = 256 = 8*32)
  const int flat = blockIdx.x;
  const int v = (flat & 7) * 32 + (flat >> 3);
  const int bn = v & 3, bm = v >> 2;
  const int m0 = bm * 256, n0 = bn * 256;

  const int tid = threadIdx.x;
  const int lane = tid & 63, w = tid >> 6;
  const int wm = w >> 2, wn = w & 3;
  const int l15 = lane & 15, l16 = lane >> 4;
  const int axor = (l15 & 7) << 4;                 // swizzle XOR (bytes)
  // u16-unit swizzled k-column offsets for frag reads
  const int acol0 = ((0 * 64 + l16 * 16) ^ axor) >> 1;   // ks=0 fragment
  const int acol1 = ((1 * 64 + l16 * 16) ^ axor) >> 1;   // ks=1 fragment
  const int arow = l15 * 64;                        // u16 units (row = l15)
  const int bbase = ((wn & 1) * 64 + l15) * 64;

  f32x4 acc[8][4] = {};

  // ---- prologue: stage A(0), B(0), B(1); drain to 4 (B(1) stays in flight)
  stage_half(A, m0 + 0 * 128, kcolA(0), sH[0], tid);
  stage_half(A, m0 + 1 * 128, kcolA(0), sH[1], tid);
  stage_half(B, n0 + 0 * 128, kcolB(0), sH[4], tid);
  stage_half(B, n0 + 1 * 128, kcolB(0), sH[5], tid);
  stage_half(B, n0 + 0 * 128, kcolB(1), sH[6], tid);
  stage_half(B, n0 + 1 * 128, kcolB(1), sH[7], tid);
  asm volatile("s_waitcnt vmcnt(4)" ::: "memory");
  BARRIER();

  for (int i = 0; i < 48; ++i) {
    const int t1 = 2 * i + 1;
    const int kA1 = kcolA(t1);
    const int kB2 = kcolB(min(2 * i + 2, 95));
    const int kA2 = kcolA(min(2 * i + 2, 95));
    const int kB3 = kcolB(min(2 * i + 3, 95));

    #pragma unroll
    for (int blk = 0; blk < 2; ++blk) {            // blk 0: tile t0/buf0, 1: t1/buf1
      const u16* aslot = sH[blk * 2 + wm];
      const u16* bslot = sH[4 + blk * 2 + (wn >> 1)];
      short8 bF[4][2];
      #pragma unroll
      for (int q = 0; q < 4; ++q) {
        // --- ds reads for this phase
        if (q == 0) {
          #pragma unroll
          for (int ni = 0; ni < 4; ++ni) {
            bF[ni][0] = *(const short8*)(bslot + bbase + ni * 1024 + acol0);
            bF[ni][1] = *(const short8*)(bslot + bbase + ni * 1024 + acol1);
          }
        }
        short8 aF[2][2];
        #pragma unroll
        for (int dm = 0; dm < 2; ++dm) {
          aF[dm][0] = *(const short8*)(aslot + (2 * q + dm) * 1024 + arow + acol0);
          aF[dm][1] = *(const short8*)(aslot + (2 * q + dm) * 1024 + arow + acol1);
        }
        // --- stage one half-tile
        if (blk == 0) {
          if (q == 0) stage_half(A, m0 + 0 * 128, kA1, sH[2], tid);
          if (q == 1) stage_half(A, m0 + 1 * 128, kA1, sH[3], tid);
          if (q == 2) stage_half(B, n0 + 0 * 128, kB2, sH[4], tid);
          if (q == 3) stage_half(B, n0 + 1 * 128, kB2, sH[5], tid);
        } else {
          if (q == 0) stage_half(A, m0 + 0 * 128, kA2, sH[0], tid);
          if (q == 1) stage_half(A, m0 + 1 * 128, kA2, sH[1], tid);
          if (q == 2) stage_half(B, n0 + 0 * 128, kB3, sH[6], tid);
          if (q == 3) stage_half(B, n0 + 1 * 128, kB3, sH[7], tid);
        }
        if (q == 3) asm volatile("s_waitcnt vmcnt(4)" ::: "memory");
        BARRIER();
        asm volatile("s_waitcnt lgkmcnt(0)" ::: "memory");
        __builtin_amdgcn_sched_barrier(0);
        __builtin_amdgcn_s_setprio(1);
        #pragma unroll
        for (int ni = 0; ni < 4; ++ni)
          #pragma unroll
          for (int s = 0; s < 2; ++s) {
            acc[2 * q][ni] = __builtin_amdgcn_mfma_f32_16x16x32_bf16(
                aF[0][s], bF[ni][s], acc[2 * q][ni], 0, 0, 0);
            acc[2 * q + 1][ni] = __builtin_amdgcn_mfma_f32_16x16x32_bf16(
                aF[1][s], bF[ni][s], acc[2 * q + 1][ni], 0, 0, 0);
          }
        __builtin_amdgcn_s_setprio(0);
        BARRIER();
      }
    }
  }
  // drain in-flight LDS-DMA before endpgm (successor block reuses this LDS)
  asm volatile("s_waitcnt vmcnt(0)" ::: "memory");

  // ---- epilogue: C/D layout col=lane&15, row=(lane>>4)*4+reg (m89-verified)
  const int crow0 = m0 + wm * 128 + l16 * 4;
  const int ccol0 = n0 + wn * 64 + l15;
  #pragma unroll
  for (int mi = 0; mi < 8; ++mi)
    #pragma unroll
    for (int ni = 0; ni < 4; ++ni)
      #pragma unroll
      for (int r = 0; r < 4; ++r)
        S[(size_t)(crow0 + mi * 16 + r) * 1024 + ccol0 + ni * 16] =
            0.5f - 0.5f * acc[mi][ni][r];
}

// ---------------------------------------------------------------------------
// Sort-free top-32 + softmax + MLP + broadcast. One wave per row.
// u32 keys (sign-transformed float bits); per round: 16-slot lane-min,
// 6-stage u32 wave-min, lowest-idx-among-matches, invalidate. Ties resolve
// to lowest idx (matches lax.top_k).
// ---------------------------------------------------------------------------
__global__ __launch_bounds__(256) void topk_mlp_bcast_kernel(
    const float* __restrict__ S, const float* __restrict__ P1,
    const float* __restrict__ b1, const float* __restrict__ w2,
    const float* __restrict__ b2, float* __restrict__ xout,
    float* __restrict__ sdout) {
  const int wid = threadIdx.x >> 6;
  const int lane = threadIdx.x & 63;
  const int b = blockIdx.x * 4 + wid;

  const float* Sr = S + (size_t)b * NPROMPT;
  u32 vkey[16];
  #pragma unroll
  for (int i = 0; i < 4; ++i) {
    float4 vv = ((const float4*)Sr)[i * 64 + lane];
    float f[4] = {vv.x, vv.y, vv.z, vv.w};
    #pragma unroll
    for (int j = 0; j < 4; ++j) {
      u32 u = __float_as_uint(f[j]);
      vkey[i * 4 + j] = (u & 0x80000000u) ? ~u : (u | 0x80000000u);
    }
  }
  const u32 ib = (u32)lane * 4u;

  float seld = 0.f;
  int selidx = 0;
  for (int r = 0; r < NSEL; ++r) {
    u32 lm = vkey[0];
    #pragma unroll
    for (int s = 1; s < 16; ++s) lm = min(lm, vkey[s]);
    u32 g = lm;
    #pragma unroll
    for (int m = 1; m < 64; m <<= 1) g = min(g, (u32)__shfl_xor((int)g, m, 64));
    // lowest idx among this lane's matches (descending overwrite)
    u32 li = 0xFFFFFFFFu;
    #pragma unroll
    for (int s = 15; s >= 0; --s)
      li = (vkey[s] == g) ? ((u32)(s >> 2) * 256u + ib + (u32)(s & 3)) : li;
    u32 gi = li;
    #pragma unroll
    for (int m = 1; m < 64; m <<= 1) gi = min(gi, (u32)__shfl_xor((int)gi, m, 64));
    if ((lane & 31) == r) {
      u32 bits = (g & 0x80000000u) ? (g ^ 0x80000000u) : ~g;
      seld = __uint_as_float(bits);
      selidx = (int)gi;
    }
    // invalidate the unique winner slot
    #pragma unroll
    for (int s = 0; s < 16; ++s) {
      u32 myidx = (u32)(s >> 2) * 256u + ib + (u32)(s & 3);
      if (vkey[s] == g && myidx == gi) vkey[s] = 0xFFFFFFFFu;
    }
  }

  if (lane < NSEL) sdout[(size_t)b * NSEL + lane] = seld;

  // softmax(1 - d) over 32 selected (max at smallest dist)
  float d0 = __shfl(seld, 0, 32);
  float e = __expf(d0 - seld);
  float sum = e;
  #pragma unroll
  for (int s = 1; s < 32; s <<= 1) sum += __shfl_xor(sum, s, 32);
  float score = e / sum;

  // h[lane] = relu((1/32) sum_r score_r * P1[idx_r][lane] + b1[lane])
  float acc = 0.f;
  #pragma unroll
  for (int r = 0; r < NSEL; ++r) {
    float sr = __shfl(score, r, 32);
    int ir = __shfl(selidx, r, 32);
    acc = fmaf(sr, P1[(size_t)ir * HID + lane], acc);
  }
  float h = fmaxf(acc * (1.0f / NSEL) + b1[lane], 0.0f);

  // o[lane] = b2[lane] + sum_hh h[hh] * w2[lane][hh]
  float o = b2[lane];
  #pragma unroll
  for (int hh = 0; hh < 64; ++hh)
    o = fmaf(__shfl(h, hh, 64), w2[lane * HID + hh], o);

  // broadcast o over 256 cloud points
  const int src = (lane & 15) * 4;
  float4 f;
  f.x = __shfl(o, src + 0, 64);
  f.y = __shfl(o, src + 1, 64);
  f.z = __shfl(o, src + 2, 64);
  f.w = __shfl(o, src + 3, 64);
  float4* xr = (float4*)(xout + (size_t)b * (NCLOUD * ODIM));
  #pragma unroll 4
  for (int i = 0; i < 64; ++i) xr[i * 64 + lane] = f;
}

// ---------------------------------------------------------------------------
extern "C" void kernel_launch(void* const* d_in, const int* in_sizes, int n_in,
                              void* d_out, int out_size, void* d_ws, size_t ws_size,
                              hipStream_t stream) {
  const float* query   = (const float*)d_in[1];
  const float* keys    = (const float*)d_in[2];
  const float* prompts = (const float*)d_in[3];
  const float* w1      = (const float*)d_in[4];
  const float* b1      = (const float*)d_in[5];
  const float* w2      = (const float*)d_in[6];
  const float* b2      = (const float*)d_in[7];

  char* ws = (char*)d_ws;
  u16*   Abig = (u16*)ws;                                       // 134217728 B
  u16*   Bbig = (u16*)(ws + 134217728);                         //   8388608 B
  float* P1   = (float*)(ws + 134217728 + 8388608);             //    262144 B
  float* S    = (float*)(ws + 134217728 + 8388608 + 262144);    //  67108864 B

  float* xout  = (float*)d_out;
  float* sdout = (float*)d_out + (size_t)B_ROWS * NCLOUD * ODIM;

  norm_split_kernel<<<B_ROWS, 256, 0, stream>>>(query, Abig);
  norm_split_kernel<<<NPROMPT, 256, 0, stream>>>(keys, Bbig);
  p1_kernel<<<NPROMPT, 256, 0, stream>>>(prompts, w1, P1);
  gemm8p_kernel<<<256, 512, 0, stream>>>(Abig, Bbig, S);
  topk_mlp_bcast_kernel<<<B_ROWS / 4, 256, 0, stream>>>(S, P1, b1, w2, b2, xout, sdout);
}